// Round 3
// baseline (825.276 us; speedup 1.0000x reference)
//
#include <hip/hip_runtime.h>
#include <math.h>

#define N_ROWS 16384
#define DIM 4096
#define NEXP 64
#define SPLITK 8
#define KSLICE (DIM / SPLITK)     // 512 k per wave
#define DT 8                      // k-depth per tile
#define NTILES (KSLICE / DT)      // 64 tiles per wave
#define ROWS_PER_BLOCK 64

// ---- global -> LDS direct (width 16); LDS dest = uniform base + lane*16 ----
__device__ __forceinline__ void load16(const float* g, float* l) {
    __builtin_amdgcn_global_load_lds(
        (const __attribute__((address_space(1))) void*)g,
        (__attribute__((address_space(3))) void*)l, 16, 0, 0);
}

__device__ __forceinline__ bool gtpair(float a, int ia, float b, int ib) {
    return (a > b) || (a == b && ia < ib);
}

// Block: 512 threads = 8 waves. Block handles 64 rows; wave wv handles k-slice
// [wv*512, wv*512+512). Lane l: g = l>>3 (rows 8i+g), le = l&7 (experts le+8j).
// acc[8][8] per lane => 16 lane-FMAs per ds_read_b128 (LDS/VALU balanced).
// Wave-private dbuf LDS tiles, no barriers in the main loop (counted vmcnt only).
__global__ __launch_bounds__(512, 2)
void gate_kernel(const float* __restrict__ x, const float* __restrict__ w,
                 float* __restrict__ out)
{
    __shared__ float lds[16384];              // 64 KB: 8 waves x 2048 floats

    const int tid  = threadIdx.x;
    const int lane = tid & 63;
    const int wv   = tid >> 6;                // 0..7 = k-split slice
    const int g    = lane >> 3;               // row group 0..7
    const int le   = lane & 7;                // expert sub-index 0..7
    const int row0 = blockIdx.x * ROWS_PER_BLOCK;
    const int kbase = wv * KSLICE;
    const int wb   = wv * 2048;               // wave LDS base (floats)
    // wave layout: x tiles at wb + buf*512 ; w tiles at wb + 1024 + buf*512

    const int rr = lane >> 1;                 // staging row within 32-row half
    const int kk = (lane & 1) * 4;            // staging k sub-offset

    float acc[8][8];
#pragma unroll
    for (int i = 0; i < 8; ++i)
#pragma unroll
        for (int j = 0; j < 8; ++j) acc[i][j] = 0.f;

    // ---- staging: 4 x global_load_lds(16B) per tile (2 for x, 2 for w) ----
    // LDS elem = base + lane*4 floats -> row = i*32 + lane/2, k = (lane&1)*4.
#define STAGE(T, BUF)                                                          \
    do {                                                                       \
        const int k0_ = kbase + (T) * DT;                                      \
        _Pragma("unroll")                                                      \
        for (int i_ = 0; i_ < 2; ++i_) {                                       \
            load16(x + (size_t)(row0 + i_ * 32 + rr) * DIM + k0_ + kk,         \
                   &lds[wb + (BUF) * 512 + i_ * 256]);                         \
            load16(w + (size_t)(i_ * 32 + rr) * DIM + k0_ + kk,               \
                   &lds[wb + 1024 + (BUF) * 512 + i_ * 256]);                  \
        }                                                                      \
    } while (0)

    STAGE(0, 0);
    STAGE(1, 1);

#pragma unroll 2
    for (int t = 0; t < NTILES; ++t) {
        const int buf = t & 1;
        if (t < NTILES - 1) asm volatile("s_waitcnt vmcnt(4)" ::: "memory");
        else                asm volatile("s_waitcnt vmcnt(0)" ::: "memory");

#pragma unroll
        for (int k4 = 0; k4 < 2; ++k4) {
            const int xbase = wb + buf * 512 + g * 8 + k4 * 4;
            const int wbase = wb + 1024 + buf * 512 + le * 8 + k4 * 4;
            float4 wf[8];
#pragma unroll
            for (int j = 0; j < 8; ++j)
                wf[j] = *reinterpret_cast<const float4*>(&lds[wbase + 64 * j]);
#pragma unroll
            for (int i = 0; i < 8; ++i) {
                float4 xv = *reinterpret_cast<const float4*>(&lds[xbase + 64 * i]);
#pragma unroll
                for (int j = 0; j < 8; ++j) {
                    acc[i][j] = fmaf(xv.x, wf[j].x, acc[i][j]);
                    acc[i][j] = fmaf(xv.y, wf[j].y, acc[i][j]);
                    acc[i][j] = fmaf(xv.z, wf[j].z, acc[i][j]);
                    acc[i][j] = fmaf(xv.w, wf[j].w, acc[i][j]);
                }
            }
        }
        if (t + 2 < NTILES) STAGE(t + 2, buf);
    }

    // ---- split-K combine: 3-round LDS tree (regions of 4096 floats) ----
    __syncthreads();
#pragma unroll
    for (int st = 4; st >= 1; st >>= 1) {
        if (wv >= st && wv < 2 * st) {
            float* reg = &lds[(wv - st) * 4096];
#pragma unroll
            for (int i = 0; i < 8; ++i)
#pragma unroll
                for (int jc = 0; jc < 2; ++jc) {
                    float4 v = make_float4(acc[i][4 * jc + 0], acc[i][4 * jc + 1],
                                           acc[i][4 * jc + 2], acc[i][4 * jc + 3]);
                    *reinterpret_cast<float4*>(&reg[i * 512 + lane * 8 + jc * 4]) = v;
                }
        }
        __syncthreads();
        if (wv < st) {
            const float* reg = &lds[wv * 4096];
#pragma unroll
            for (int i = 0; i < 8; ++i)
#pragma unroll
                for (int jc = 0; jc < 2; ++jc) {
                    float4 v = *reinterpret_cast<const float4*>(&reg[i * 512 + lane * 8 + jc * 4]);
                    acc[i][4 * jc + 0] += v.x;
                    acc[i][4 * jc + 1] += v.y;
                    acc[i][4 * jc + 2] += v.z;
                    acc[i][4 * jc + 3] += v.w;
                }
        }
        __syncthreads();
    }

    if (wv != 0) return;

    // ---- epilogue (wave 0): softmax + top-2 per row (8 lanes per row) ----
    float* out_vals = out;                          // [N][2]
    float* out_idx  = out + (size_t)N_ROWS * 2;     // [N][2] (as float)
    float* out_sc   = out + (size_t)N_ROWS * 4;     // [N][64]

#pragma unroll
    for (int i = 0; i < 8; ++i) {
        const int row = row0 + 8 * i + g;
        float m = acc[i][0];
#pragma unroll
        for (int j = 1; j < 8; ++j) m = fmaxf(m, acc[i][j]);
#pragma unroll
        for (int mk = 1; mk <= 4; mk <<= 1) m = fmaxf(m, __shfl_xor(m, mk));
        float e[8], s = 0.f;
#pragma unroll
        for (int j = 0; j < 8; ++j) { e[j] = expf(acc[i][j] - m); s += e[j]; }
#pragma unroll
        for (int mk = 1; mk <= 4; mk <<= 1) s += __shfl_xor(s, mk);
        const float inv = 1.f / s;
        float p[8];
#pragma unroll
        for (int j = 0; j < 8; ++j) {
            p[j] = e[j] * inv;
            out_sc[(size_t)row * 64 + le + 8 * j] = p[j];
        }
        // in-lane top-2 (indices le+8j ascending; strict > keeps lowest index on tie)
        float v1 = p[0], v2 = -1.f; int i1 = le, i2 = 0;
#pragma unroll
        for (int j = 1; j < 8; ++j) {
            const int idx = le + 8 * j;
            if (p[j] > v1)      { v2 = v1; i2 = i1; v1 = p[j]; i1 = idx; }
            else if (p[j] > v2) { v2 = p[j]; i2 = idx; }
        }
        // merge across the 8-lane octet (xor masks 1,2,4)
#pragma unroll
        for (int mk = 1; mk <= 4; mk <<= 1) {
            float o1 = __shfl_xor(v1, mk); int oi1 = __shfl_xor(i1, mk);
            float o2 = __shfl_xor(v2, mk); int oi2 = __shfl_xor(i2, mk);
            if (gtpair(o1, oi1, v1, i1)) {
                if (gtpair(v1, i1, o2, oi2)) { v2 = v1; i2 = i1; }
                else                         { v2 = o2; i2 = oi2; }
                v1 = o1; i1 = oi1;
            } else if (gtpair(o1, oi1, v2, i2)) {
                v2 = o1; i2 = oi1;
            }
        }
        if (le == 0) {
            out_vals[(size_t)row * 2 + 0] = v1;     // ROUTE_SCALE == 1.0
            out_vals[(size_t)row * 2 + 1] = v2;
            out_idx[(size_t)row * 2 + 0]  = (float)i1;
            out_idx[(size_t)row * 2 + 1]  = (float)i2;
        }
    }
}

extern "C" void kernel_launch(void* const* d_in, const int* in_sizes, int n_in,
                              void* d_out, int out_size, void* d_ws, size_t ws_size,
                              hipStream_t stream)
{
    const float* x = (const float*)d_in[0];
    const float* w = (const float*)d_in[1];
    float* out = (float*)d_out;
    dim3 grid(N_ROWS / ROWS_PER_BLOCK);   // 256
    dim3 block(512);
    gate_kernel<<<grid, block, 0, stream>>>(x, w, out);
}

// Round 4
// 250.676 us; speedup vs baseline: 3.2922x; 3.2922x over previous
//
#include <hip/hip_runtime.h>
#include <math.h>

#define N_ROWS 16384
#define DIM 4096
#define NEXP 64
#define KWAVES 4
#define KSLICE (DIM / KWAVES)   // 1024 k per wave
#define KC 16                   // k per chunk
#define NCHUNK (KSLICE / KC)    // 64
#define RPB 32                  // rows per block

__device__ __forceinline__ void load16(const float* g, float* l) {
    __builtin_amdgcn_global_load_lds(
        (const __attribute__((address_space(1))) void*)g,
        (__attribute__((address_space(3))) void*)l, 16, 0, 0);
}

__device__ __forceinline__ bool gtpair(float a, int ia, float b, int ib) {
    return (a > b) || (a == b && ia < ib);
}

// Block: 4 waves x 64 lanes. lane = expert. Wave wv covers k in [wv*1024, wv*1024+1024)
// for the block's 32 rows. acc[r] = partial score[row r][expert=lane].
// Per-wave LDS (floats, base wb=wv*3072): x dbuf 2x512 ([32r][16k] row-major),
// W dbuf 2x1024 at +1024 ([4kq][64e][4k]).
__global__ __launch_bounds__(256, 2)
void gate_kernel(const float* __restrict__ x, const float* __restrict__ w,
                 float* __restrict__ out)
{
    __shared__ float lds[12288];   // 48 KB
    const int tid  = threadIdx.x;
    const int lane = tid & 63;
    const int wv   = tid >> 6;
    const int row0 = blockIdx.x * RPB;
    const int wb   = wv * 3072;
    const int kbase = wv * KSLICE;

    float acc[RPB];
#pragma unroll
    for (int r = 0; r < RPB; ++r) acc[r] = 0.f;

    // staging lane mapping: x: lane -> (row = 16*i + lane/4, 16B k-quarter lane&3)
    const int xr = lane >> 2;
    const int xk = (lane & 3) * 4;
    const float* xg = x + (size_t)(row0 + xr) * DIM + kbase + xk;
    const float* wg = w + (size_t)lane * DIM + kbase;

#define STAGE(T, B)                                                            \
    do {                                                                       \
        const int ko_ = (T) * KC;                                              \
        load16(xg + ko_,          &lds[wb + (B) * 512 + 0]);                   \
        load16(xg + 16 * DIM + ko_, &lds[wb + (B) * 512 + 256]);               \
        load16(wg + ko_ + 0,      &lds[wb + 1024 + (B) * 1024 + 0]);           \
        load16(wg + ko_ + 4,      &lds[wb + 1024 + (B) * 1024 + 256]);         \
        load16(wg + ko_ + 8,      &lds[wb + 1024 + (B) * 1024 + 512]);         \
        load16(wg + ko_ + 12,     &lds[wb + 1024 + (B) * 1024 + 768]);         \
    } while (0)

#define FMA4(XV, WF) do {                                                      \
        acc[r] = fmaf((XV).x, (WF).x, acc[r]);                                 \
        acc[r] = fmaf((XV).y, (WF).y, acc[r]);                                 \
        acc[r] = fmaf((XV).z, (WF).z, acc[r]);                                 \
        acc[r] = fmaf((XV).w, (WF).w, acc[r]);                                 \
    } while (0)

#define COMPUTE(B)                                                             \
    do {                                                                       \
        const int wbb_ = wb + 1024 + (B) * 1024 + lane * 4;                    \
        float4 wf0 = *reinterpret_cast<const float4*>(&lds[wbb_ + 0]);         \
        float4 wf1 = *reinterpret_cast<const float4*>(&lds[wbb_ + 256]);       \
        float4 wf2 = *reinterpret_cast<const float4*>(&lds[wbb_ + 512]);       \
        float4 wf3 = *reinterpret_cast<const float4*>(&lds[wbb_ + 768]);       \
        _Pragma("unroll")                                                      \
        for (int r = 0; r < RPB; ++r) {                                        \
            const float* xb_ = &lds[wb + (B) * 512 + r * 16];                  \
            float4 x0 = *reinterpret_cast<const float4*>(xb_ + 0);             \
            float4 x1 = *reinterpret_cast<const float4*>(xb_ + 4);             \
            float4 x2 = *reinterpret_cast<const float4*>(xb_ + 8);             \
            float4 x3 = *reinterpret_cast<const float4*>(xb_ + 12);            \
            FMA4(x0, wf0); FMA4(x1, wf1); FMA4(x2, wf2); FMA4(x3, wf3);        \
        }                                                                      \
    } while (0)

    STAGE(0, 0);
    STAGE(1, 1);
    for (int t = 0; t < NCHUNK - 2; t += 2) {
        asm volatile("s_waitcnt vmcnt(6)" ::: "memory");   // chunk t staged
        COMPUTE(0);
        asm volatile("s_waitcnt lgkmcnt(0)" ::: "memory"); // buf0 reads retired
        STAGE(t + 2, 0);
        asm volatile("s_waitcnt vmcnt(6)" ::: "memory");   // chunk t+1 staged
        COMPUTE(1);
        asm volatile("s_waitcnt lgkmcnt(0)" ::: "memory");
        STAGE(t + 3, 1);
    }
    asm volatile("s_waitcnt vmcnt(6)" ::: "memory");
    COMPUTE(0);
    asm volatile("s_waitcnt vmcnt(0)" ::: "memory");
    COMPUTE(1);

    // ---- combine the 4 k-slices via LDS regions [wv][32r][64e] ----
    __syncthreads();
#pragma unroll
    for (int r = 0; r < RPB; ++r) lds[wv * 2048 + r * 64 + lane] = acc[r];
    __syncthreads();

    float* out_vals = out;                          // [N][2]
    float* out_idx  = out + (size_t)N_ROWS * 2;     // [N][2] (as float)
    float* out_sc   = out + (size_t)N_ROWS * 4;     // [N][64]

    // wave wv finalizes rows wv*8 .. wv*8+7
#pragma unroll
    for (int i = 0; i < 8; ++i) {
        const int r = wv * 8 + i;
        const int row = row0 + r;
        float s = lds[r * 64 + lane] + lds[2048 + r * 64 + lane]
                + lds[4096 + r * 64 + lane] + lds[6144 + r * 64 + lane];
        float m = s;
#pragma unroll
        for (int off = 32; off; off >>= 1) m = fmaxf(m, __shfl_xor(m, off));
        float e = expf(s - m);
        float sum = e;
#pragma unroll
        for (int off = 32; off; off >>= 1) sum += __shfl_xor(sum, off);
        float p = e / sum;
        out_sc[(size_t)row * 64 + lane] = p;

        // top-2 butterfly over 64 lanes (tie -> lowest index, matching lax.top_k)
        float v1 = p; int i1 = lane; float v2 = -1.f; int i2 = lane;
#pragma unroll
        for (int off = 32; off; off >>= 1) {
            float o1 = __shfl_xor(v1, off); int oi1 = __shfl_xor(i1, off);
            float o2 = __shfl_xor(v2, off); int oi2 = __shfl_xor(i2, off);
            if (gtpair(o1, oi1, v1, i1)) {
                if (gtpair(v1, i1, o2, oi2)) { v2 = v1; i2 = i1; }
                else                         { v2 = o2; i2 = oi2; }
                v1 = o1; i1 = oi1;
            } else if (gtpair(o1, oi1, v2, i2)) {
                v2 = o1; i2 = oi1;
            }
        }
        if (lane == 0) {
            out_vals[(size_t)row * 2 + 0] = v1;     // ROUTE_SCALE == 1.0
            out_vals[(size_t)row * 2 + 1] = v2;
            out_idx[(size_t)row * 2 + 0]  = (float)i1;
            out_idx[(size_t)row * 2 + 1]  = (float)i2;
        }
    }
}

extern "C" void kernel_launch(void* const* d_in, const int* in_sizes, int n_in,
                              void* d_out, int out_size, void* d_ws, size_t ws_size,
                              hipStream_t stream)
{
    const float* x = (const float*)d_in[0];
    const float* w = (const float*)d_in[1];
    float* out = (float*)d_out;
    dim3 grid(N_ROWS / RPB);   // 512
    dim3 block(256);
    gate_kernel<<<grid, block, 0, stream>>>(x, w, out);
}

// Round 6
// 99.853 us; speedup vs baseline: 8.2649x; 2.5104x over previous
//
#include <hip/hip_runtime.h>
#include <math.h>

#define N_ROWS 16384
#define DIM 4096
#define NEXP 64
#define KWAVES 4
#define KSLICE (DIM / KWAVES)      // 1024 k per wave
#define KC 32                      // k per chunk (one MFMA K-step)
#define NCHUNK (KSLICE / KC)       // 32
#define RPB 32                     // rows per block (2 M-tiles per wave)
#define NKO (DIM / 8)              // 512 k-octets

typedef short short8 __attribute__((ext_vector_type(8)));
typedef float f32x4  __attribute__((ext_vector_type(4)));

__device__ __forceinline__ unsigned cvt_pk_bf16(float a, float b) {
    unsigned r;
    asm("v_cvt_pk_bf16_f32 %0, %1, %2" : "=v"(r) : "v"(a), "v"(b));
    return r;   // low16 = bf16(a), high16 = bf16(b)
}

// 3-way split of 8 f32 into bf16 hi/mid/lo frags. Each residual subtraction is
// Sterbenz-exact, so x = h + m + l + eps with |eps| <= 2^-27 |x|.
__device__ __forceinline__ void split3(const float* xv, short8& h8, short8& m8, short8& l8) {
    union { unsigned u[4]; short8 s; } H, M, L;
#pragma unroll
    for (int j = 0; j < 4; ++j) {
        float a = xv[2 * j], b = xv[2 * j + 1];
        unsigned hp = cvt_pk_bf16(a, b);
        float a1 = a - __uint_as_float(hp << 16);
        float b1 = b - __uint_as_float(hp & 0xffff0000u);
        unsigned mp = cvt_pk_bf16(a1, b1);
        float a2 = a1 - __uint_as_float(mp << 16);
        float b2 = b1 - __uint_as_float(mp & 0xffff0000u);
        H.u[j] = hp; M.u[j] = mp; L.u[j] = cvt_pk_bf16(a2, b2);
    }
    h8 = H.s; m8 = M.s; l8 = L.s;
}

__device__ __forceinline__ bool gtpair(float a, int ia, float b, int ib) {
    return (a > b) || (a == b && ia < ib);
}

// ---- pre-kernel: W[64][4096] f32 -> three bf16 tables [ko][e] (k-octet packed) ----
__global__ __launch_bounds__(256)
void convw_kernel(const float* __restrict__ w, short8* __restrict__ w0t,
                  short8* __restrict__ w1t, short8* __restrict__ w2t)
{
    const int t  = blockIdx.x * 256 + threadIdx.x;   // 32768 = 512 ko x 64 e
    const int ko = t >> 6;
    const int e  = t & 63;
    const float* src = w + (size_t)e * DIM + ko * 8;
    float xv[8];
#pragma unroll
    for (int j = 0; j < 8; ++j) xv[j] = src[j];
    short8 h, m, l;
    split3(xv, h, m, l);
    w0t[ko * 64 + e] = h;
    w1t[ko * 64 + e] = m;
    w2t[ko * 64 + e] = l;
}

// ---- main: 512 blocks x 4 waves; wave wv covers k-slice wv*1024..+1024 for
// the block's 32 rows (2 M-tiles of 16). A-frag: row = lane&15, k-octet g =
// lane>>4 (A/B share the k-order => any consistent order is valid). C-frag
// (m89-verified): col = lane&15, row = (lane>>4)*4 + reg.
__global__ __launch_bounds__(256, 2)
void gate_kernel(const float* __restrict__ x, const short8* __restrict__ w0t,
                 const short8* __restrict__ w1t, const short8* __restrict__ w2t,
                 float* __restrict__ out)
{
    __shared__ float part[KWAVES][RPB][NEXP + 1];   // stride 65, 33.3 KB

    const int tid  = threadIdx.x;
    const int lane = tid & 63;
    const int wv   = tid >> 6;
    const int l15  = lane & 15;
    const int g    = lane >> 4;
    const int row0 = blockIdx.x * RPB;

    f32x4 acc[2][4];
#pragma unroll
    for (int mt = 0; mt < 2; ++mt)
#pragma unroll
        for (int nt = 0; nt < 4; ++nt) acc[mt][nt] = (f32x4){0.f, 0.f, 0.f, 0.f};

    const float* xp0 = x + (size_t)(row0 + l15) * DIM + wv * KSLICE + g * 8;
    const float* xp1 = xp0 + 16 * DIM;

    float4 c00 = *reinterpret_cast<const float4*>(xp0);
    float4 c01 = *reinterpret_cast<const float4*>(xp0 + 4);
    float4 c10 = *reinterpret_cast<const float4*>(xp1);
    float4 c11 = *reinterpret_cast<const float4*>(xp1 + 4);

    for (int t = 0; t < NCHUNK; ++t) {
        // prefetch next chunk's x (clamped on last iter; harmless reload)
        const int tn = (t < NCHUNK - 1 ? t + 1 : t) * KC;
        float4 n00 = *reinterpret_cast<const float4*>(xp0 + tn);
        float4 n01 = *reinterpret_cast<const float4*>(xp0 + tn + 4);
        float4 n10 = *reinterpret_cast<const float4*>(xp1 + tn);
        float4 n11 = *reinterpret_cast<const float4*>(xp1 + tn + 4);

        float v0[8] = {c00.x, c00.y, c00.z, c00.w, c01.x, c01.y, c01.z, c01.w};
        float v1[8] = {c10.x, c10.y, c10.z, c10.w, c11.x, c11.y, c11.z, c11.w};
        short8 a0h, a0m, a0l, a1h, a1m, a1l;
        split3(v0, a0h, a0m, a0l);
        split3(v1, a1h, a1m, a1l);

        const int base = (wv * 128 + t * 4 + g) * 64 + l15;
#pragma unroll
        for (int nt = 0; nt < 4; ++nt) {
            short8 b0 = w0t[base + nt * 16];
            short8 b1 = w1t[base + nt * 16];
            short8 b2 = w2t[base + nt * 16];
            // smallest terms first
            acc[0][nt] = __builtin_amdgcn_mfma_f32_16x16x32_bf16(a0l, b0, acc[0][nt], 0, 0, 0);
            acc[0][nt] = __builtin_amdgcn_mfma_f32_16x16x32_bf16(a0m, b1, acc[0][nt], 0, 0, 0);
            acc[0][nt] = __builtin_amdgcn_mfma_f32_16x16x32_bf16(a0h, b2, acc[0][nt], 0, 0, 0);
            acc[0][nt] = __builtin_amdgcn_mfma_f32_16x16x32_bf16(a0m, b0, acc[0][nt], 0, 0, 0);
            acc[0][nt] = __builtin_amdgcn_mfma_f32_16x16x32_bf16(a0h, b1, acc[0][nt], 0, 0, 0);
            acc[0][nt] = __builtin_amdgcn_mfma_f32_16x16x32_bf16(a0h, b0, acc[0][nt], 0, 0, 0);

            acc[1][nt] = __builtin_amdgcn_mfma_f32_16x16x32_bf16(a1l, b0, acc[1][nt], 0, 0, 0);
            acc[1][nt] = __builtin_amdgcn_mfma_f32_16x16x32_bf16(a1m, b1, acc[1][nt], 0, 0, 0);
            acc[1][nt] = __builtin_amdgcn_mfma_f32_16x16x32_bf16(a1h, b2, acc[1][nt], 0, 0, 0);
            acc[1][nt] = __builtin_amdgcn_mfma_f32_16x16x32_bf16(a1m, b0, acc[1][nt], 0, 0, 0);
            acc[1][nt] = __builtin_amdgcn_mfma_f32_16x16x32_bf16(a1h, b1, acc[1][nt], 0, 0, 0);
            acc[1][nt] = __builtin_amdgcn_mfma_f32_16x16x32_bf16(a1h, b0, acc[1][nt], 0, 0, 0);
        }
        c00 = n00; c01 = n01; c10 = n10; c11 = n11;
    }

    // ---- split-K partials to LDS ----
#pragma unroll
    for (int mt = 0; mt < 2; ++mt)
#pragma unroll
        for (int nt = 0; nt < 4; ++nt)
#pragma unroll
            for (int r = 0; r < 4; ++r)
                part[wv][mt * 16 + g * 4 + r][nt * 16 + l15] = acc[mt][nt][r];
    __syncthreads();

    float* out_vals = out;                          // [N][2]
    float* out_idx  = out + (size_t)N_ROWS * 2;     // [N][2] (as float)
    float* out_sc   = out + (size_t)N_ROWS * 4;     // [N][64]

    // wave wv finalizes rows wv*8 .. wv*8+7; lane = expert
#pragma unroll
    for (int i = 0; i < 8; ++i) {
        const int r = wv * 8 + i;
        const int row = row0 + r;
        float s = part[0][r][lane] + part[1][r][lane]
                + part[2][r][lane] + part[3][r][lane];
        float m = s;
#pragma unroll
        for (int off = 32; off; off >>= 1) m = fmaxf(m, __shfl_xor(m, off));
        float e = expf(s - m);
        float sum = e;
#pragma unroll
        for (int off = 32; off; off >>= 1) sum += __shfl_xor(sum, off);
        float p = e / sum;
        out_sc[(size_t)row * 64 + lane] = p;

        // top-2 butterfly over 64 lanes (tie -> lowest index, matches lax.top_k)
        float v1 = p; int i1 = lane; float v2 = -1.f; int i2 = lane;
#pragma unroll
        for (int off = 32; off; off >>= 1) {
            float o1 = __shfl_xor(v1, off); int oi1 = __shfl_xor(i1, off);
            float o2 = __shfl_xor(v2, off); int oi2 = __shfl_xor(i2, off);
            if (gtpair(o1, oi1, v1, i1)) {
                if (gtpair(v1, i1, o2, oi2)) { v2 = v1; i2 = i1; }
                else                         { v2 = o2; i2 = oi2; }
                v1 = o1; i1 = oi1;
            } else if (gtpair(o1, oi1, v2, i2)) {
                v2 = o1; i2 = oi1;
            }
        }
        if (lane == 0) {
            out_vals[(size_t)row * 2 + 0] = v1;     // ROUTE_SCALE == 1.0
            out_vals[(size_t)row * 2 + 1] = v2;
            out_idx[(size_t)row * 2 + 0]  = (float)i1;
            out_idx[(size_t)row * 2 + 1]  = (float)i2;
        }
    }
}

extern "C" void kernel_launch(void* const* d_in, const int* in_sizes, int n_in,
                              void* d_out, int out_size, void* d_ws, size_t ws_size,
                              hipStream_t stream)
{
    const float* x = (const float*)d_in[0];
    const float* w = (const float*)d_in[1];
    float* out = (float*)d_out;

    short8* w0t = (short8*)d_ws;            // 512 KB
    short8* w1t = w0t + NKO * NEXP;         // 512 KB
    short8* w2t = w1t + NKO * NEXP;         // 512 KB

    convw_kernel<<<dim3(128), dim3(256), 0, stream>>>(w, w0t, w1t, w2t);
    gate_kernel<<<dim3(N_ROWS / RPB), dim3(256), 0, stream>>>(x, w0t, w1t, w2t, out);
}

// Round 7
// 87.012 us; speedup vs baseline: 9.4846x; 1.1476x over previous
//
#include <hip/hip_runtime.h>
#include <math.h>

#define N_ROWS 16384
#define DIM 4096
#define NEXP 64
#define KWAVES 8
#define KSLICE (DIM / KWAVES)      // 512 k per wave
#define KC 32                      // k per chunk (one MFMA K-step)
#define NCHUNK (KSLICE / KC)       // 16
#define RPB 32                     // rows per block (2 M-tiles per wave)
#define NKO (DIM / 8)              // 512 k-octets

typedef short short8 __attribute__((ext_vector_type(8)));
typedef float f32x4  __attribute__((ext_vector_type(4)));

__device__ __forceinline__ unsigned cvt_pk_bf16(float a, float b) {
    unsigned r;
    asm("v_cvt_pk_bf16_f32 %0, %1, %2" : "=v"(r) : "v"(a), "v"(b));
    return r;   // low16 = bf16(a), high16 = bf16(b)
}

// 3-way split of 8 f32 into bf16 hi/mid/lo frags. Residual subtractions are
// exact, so x = h + m + l + eps with |eps| <= 2^-27 |x|.
__device__ __forceinline__ void split3(const float* xv, short8& h8, short8& m8, short8& l8) {
    union { unsigned u[4]; short8 s; } H, M, L;
#pragma unroll
    for (int j = 0; j < 4; ++j) {
        float a = xv[2 * j], b = xv[2 * j + 1];
        unsigned hp = cvt_pk_bf16(a, b);
        float a1 = a - __uint_as_float(hp << 16);
        float b1 = b - __uint_as_float(hp & 0xffff0000u);
        unsigned mp = cvt_pk_bf16(a1, b1);
        float a2 = a1 - __uint_as_float(mp << 16);
        float b2 = b1 - __uint_as_float(mp & 0xffff0000u);
        H.u[j] = hp; M.u[j] = mp; L.u[j] = cvt_pk_bf16(a2, b2);
    }
    h8 = H.s; m8 = M.s; l8 = L.s;
}

__device__ __forceinline__ bool gtpair(float a, int ia, float b, int ib) {
    return (a > b) || (a == b && ia < ib);
}

// ---- pre-kernel: W[64][4096] f32 -> three bf16 tables [ko][e] (k-octet packed) ----
__global__ __launch_bounds__(256)
void convw_kernel(const float* __restrict__ w, short8* __restrict__ w0t,
                  short8* __restrict__ w1t, short8* __restrict__ w2t)
{
    const int t  = blockIdx.x * 256 + threadIdx.x;   // 32768 = 512 ko x 64 e
    const int ko = t >> 6;
    const int e  = t & 63;
    const float* src = w + (size_t)e * DIM + ko * 8;
    float xv[8];
#pragma unroll
    for (int j = 0; j < 8; ++j) xv[j] = src[j];
    short8 h, m, l;
    split3(xv, h, m, l);
    w0t[ko * 64 + e] = h;
    w1t[ko * 64 + e] = m;
    w2t[ko * 64 + e] = l;
}

// ---- main: 512 blocks x 8 waves; wave wv covers k-slice wv*512..+512 for the
// block's 32 rows (2 M-tiles of 16). A-frag: row = lane&15, k-octet g = lane>>4
// (A/B share the k-order => any consistent order is valid). C-frag
// (m89-verified): col = lane&15, row = (lane>>4)*4 + reg.
__global__ __launch_bounds__(512, 4)
void gate_kernel(const float* __restrict__ x, const short8* __restrict__ w0t,
                 const short8* __restrict__ w1t, const short8* __restrict__ w2t,
                 float* __restrict__ out)
{
    __shared__ float part[KWAVES][RPB][NEXP];   // 64 KB exactly

    const int tid  = threadIdx.x;
    const int lane = tid & 63;
    const int wv   = tid >> 6;                  // 0..7 = k-slice
    const int l15  = lane & 15;
    const int g    = lane >> 4;
    const int row0 = blockIdx.x * RPB;

    f32x4 acc[2][4];
#pragma unroll
    for (int mt = 0; mt < 2; ++mt)
#pragma unroll
        for (int nt = 0; nt < 4; ++nt) acc[mt][nt] = (f32x4){0.f, 0.f, 0.f, 0.f};

    const float* xp0 = x + (size_t)(row0 + l15) * DIM + wv * KSLICE + g * 8;
    const float* xp1 = xp0 + 16 * DIM;

    float4 c00 = *reinterpret_cast<const float4*>(xp0);
    float4 c01 = *reinterpret_cast<const float4*>(xp0 + 4);
    float4 c10 = *reinterpret_cast<const float4*>(xp1);
    float4 c11 = *reinterpret_cast<const float4*>(xp1 + 4);

    for (int t = 0; t < NCHUNK; ++t) {
        // prefetch next chunk's x (clamped on last iter; harmless reload)
        const int tn = (t < NCHUNK - 1 ? t + 1 : t) * KC;
        float4 n00 = *reinterpret_cast<const float4*>(xp0 + tn);
        float4 n01 = *reinterpret_cast<const float4*>(xp0 + tn + 4);
        float4 n10 = *reinterpret_cast<const float4*>(xp1 + tn);
        float4 n11 = *reinterpret_cast<const float4*>(xp1 + tn + 4);

        float v0[8] = {c00.x, c00.y, c00.z, c00.w, c01.x, c01.y, c01.z, c01.w};
        float v1[8] = {c10.x, c10.y, c10.z, c10.w, c11.x, c11.y, c11.z, c11.w};
        short8 a0h, a0m, a0l, a1h, a1m, a1l;
        split3(v0, a0h, a0m, a0l);
        split3(v1, a1h, a1m, a1l);

        const int base = (wv * 64 + t * 4 + g) * 64 + l15;
#pragma unroll
        for (int nt = 0; nt < 4; ++nt) {
            short8 b0 = w0t[base + nt * 16];
            short8 b1 = w1t[base + nt * 16];
            short8 b2 = w2t[base + nt * 16];
            acc[0][nt] = __builtin_amdgcn_mfma_f32_16x16x32_bf16(a0l, b0, acc[0][nt], 0, 0, 0);
            acc[0][nt] = __builtin_amdgcn_mfma_f32_16x16x32_bf16(a0m, b1, acc[0][nt], 0, 0, 0);
            acc[0][nt] = __builtin_amdgcn_mfma_f32_16x16x32_bf16(a0h, b2, acc[0][nt], 0, 0, 0);
            acc[0][nt] = __builtin_amdgcn_mfma_f32_16x16x32_bf16(a0m, b0, acc[0][nt], 0, 0, 0);
            acc[0][nt] = __builtin_amdgcn_mfma_f32_16x16x32_bf16(a0h, b1, acc[0][nt], 0, 0, 0);
            acc[0][nt] = __builtin_amdgcn_mfma_f32_16x16x32_bf16(a0h, b0, acc[0][nt], 0, 0, 0);

            acc[1][nt] = __builtin_amdgcn_mfma_f32_16x16x32_bf16(a1l, b0, acc[1][nt], 0, 0, 0);
            acc[1][nt] = __builtin_amdgcn_mfma_f32_16x16x32_bf16(a1m, b1, acc[1][nt], 0, 0, 0);
            acc[1][nt] = __builtin_amdgcn_mfma_f32_16x16x32_bf16(a1h, b2, acc[1][nt], 0, 0, 0);
            acc[1][nt] = __builtin_amdgcn_mfma_f32_16x16x32_bf16(a1m, b0, acc[1][nt], 0, 0, 0);
            acc[1][nt] = __builtin_amdgcn_mfma_f32_16x16x32_bf16(a1h, b1, acc[1][nt], 0, 0, 0);
            acc[1][nt] = __builtin_amdgcn_mfma_f32_16x16x32_bf16(a1h, b0, acc[1][nt], 0, 0, 0);
        }
        c00 = n00; c01 = n01; c10 = n10; c11 = n11;
    }

    // ---- split-K partials to LDS (column XOR-swizzled by g => conflict-free) ----
#pragma unroll
    for (int mt = 0; mt < 2; ++mt)
#pragma unroll
        for (int nt = 0; nt < 4; ++nt)
#pragma unroll
            for (int r = 0; r < 4; ++r) {
                const int rw = mt * 16 + g * 4 + r;
                const int cl = (nt * 16 + l15) ^ (((rw >> 2) & 3) << 4);
                part[wv][rw][cl] = acc[mt][nt][r];
            }
    __syncthreads();

    float* out_vals = out;                          // [N][2]
    float* out_idx  = out + (size_t)N_ROWS * 2;     // [N][2] (as float)
    float* out_sc   = out + (size_t)N_ROWS * 4;     // [N][64]

    // wave wv finalizes rows wv*4 .. wv*4+3; lane = expert
#pragma unroll
    for (int i = 0; i < 4; ++i) {
        const int r = wv * 4 + i;
        const int row = row0 + r;
        const int cl = lane ^ (((r >> 2) & 3) << 4);
        float s = 0.f;
#pragma unroll
        for (int kw = 0; kw < KWAVES; ++kw) s += part[kw][r][cl];
        float m = s;
#pragma unroll
        for (int off = 32; off; off >>= 1) m = fmaxf(m, __shfl_xor(m, off));
        float e = expf(s - m);
        float sum = e;
#pragma unroll
        for (int off = 32; off; off >>= 1) sum += __shfl_xor(sum, off);
        float p = e / sum;
        out_sc[(size_t)row * 64 + lane] = p;

        // top-2 butterfly over 64 lanes (tie -> lowest index, matches lax.top_k)
        float v1 = p; int i1 = lane; float v2 = -1.f; int i2 = lane;
#pragma unroll
        for (int off = 32; off; off >>= 1) {
            float o1 = __shfl_xor(v1, off); int oi1 = __shfl_xor(i1, off);
            float o2 = __shfl_xor(v2, off); int oi2 = __shfl_xor(i2, off);
            if (gtpair(o1, oi1, v1, i1)) {
                if (gtpair(v1, i1, o2, oi2)) { v2 = v1; i2 = i1; }
                else                         { v2 = o2; i2 = oi2; }
                v1 = o1; i1 = oi1;
            } else if (gtpair(o1, oi1, v2, i2)) {
                v2 = o1; i2 = oi1;
            }
        }
        if (lane == 0) {
            out_vals[(size_t)row * 2 + 0] = v1;     // ROUTE_SCALE == 1.0
            out_vals[(size_t)row * 2 + 1] = v2;
            out_idx[(size_t)row * 2 + 0]  = (float)i1;
            out_idx[(size_t)row * 2 + 1]  = (float)i2;
        }
    }
}

extern "C" void kernel_launch(void* const* d_in, const int* in_sizes, int n_in,
                              void* d_out, int out_size, void* d_ws, size_t ws_size,
                              hipStream_t stream)
{
    const float* x = (const float*)d_in[0];
    const float* w = (const float*)d_in[1];
    float* out = (float*)d_out;

    short8* w0t = (short8*)d_ws;            // 512 KB
    short8* w1t = w0t + NKO * NEXP;         // 512 KB
    short8* w2t = w1t + NKO * NEXP;         // 512 KB

    convw_kernel<<<dim3(128), dim3(256), 0, stream>>>(w, w0t, w1t, w2t);
    gate_kernel<<<dim3(N_ROWS / RPB), dim3(512), 0, stream>>>(x, w0t, w1t, w2t, out);
}